// Round 1
// baseline (342.963 us; speedup 1.0000x reference)
//
#include <hip/hip_runtime.h>

// ---------- types / helpers ----------
typedef __bf16 bf16x8 __attribute__((ext_vector_type(8)));
typedef float  f32x4  __attribute__((ext_vector_type(4)));

__device__ __forceinline__ float b2f(unsigned short u) {
  union { float f; unsigned int i; } v; v.i = ((unsigned int)u) << 16; return v.f;
}
__device__ __forceinline__ unsigned short f2b(float f) {
  union { float f; unsigned int i; } v; v.f = f;
  unsigned int r = v.i + 0x7fffu + ((v.i >> 16) & 1u);   // RNE
  return (unsigned short)(r >> 16);
}

__device__ __forceinline__ void async_copy16(const unsigned short* g, unsigned short* l) {
  __builtin_amdgcn_global_load_lds(
      (__attribute__((address_space(1))) void*)g,
      (__attribute__((address_space(3))) void*)l, 16, 0, 0);
}

// ---------- weight prep: transpose+cast 7 f32 [K][N] -> bf16 [N][K] ----------
__global__ void k_prep_w(const float* w0, const float* w1_, const float* w2_,
                         const float* w3_, const float* w4_, const float* w5_,
                         const float* w6_, unsigned short* dst) {
  const float* srcs[7] = {w0, w1_, w2_, w3_, w4_, w5_, w6_};
  const float* src = srcs[blockIdx.z];
  unsigned short* d = dst + ((size_t)blockIdx.z << 20);
  __shared__ float tile[32][33];
  const int bn = blockIdx.x << 5, bk = blockIdx.y << 5;
  const int tx = threadIdx.x, ty = threadIdx.y;   // 32 x 8
#pragma unroll
  for (int i = 0; i < 4; ++i)
    tile[ty + i * 8][tx] = src[(size_t)(bk + ty + i * 8) * 1024 + bn + tx];
  __syncthreads();
#pragma unroll
  for (int i = 0; i < 4; ++i)
    d[(size_t)(bn + ty + i * 8) * 1024 + bk + tx] = f2b(tile[tx][ty + i * 8]);
}

// ---------- cast x [8,1022,1024] f32 -> xb [8,1024,1024] bf16 (rows 1022/1023 zero) ----------
__global__ void k_cast_x(const float* __restrict__ x, unsigned short* __restrict__ xb) {
  const size_t i = ((size_t)blockIdx.x * 256 + threadIdx.x) << 2;
  const int d = (int)(i & 1023);
  const int row = (int)(i >> 10);
  const int t = row & 1023, b = row >> 10;
  float4 v = make_float4(0.f, 0.f, 0.f, 0.f);
  if (t < 1022) v = *(const float4*)&x[((size_t)(b * 1022 + t) << 10) + d];
  ushort4 o;
  o.x = f2b(v.x); o.y = f2b(v.y); o.z = f2b(v.z); o.w = f2b(v.w);
  *(ushort4*)&xb[i] = o;
}

// ---------- depthwise conv (k=3, pad handled by zero rows + guard) + silu ----------
__global__ void k_conv_silu(const unsigned short* __restrict__ x1, const float* __restrict__ cw,
                            const float* __restrict__ cb, unsigned short* __restrict__ xs) {
  const int d = blockIdx.y * 256 + threadIdx.x;
  const int row = blockIdx.x;              // 0..8191
  const int b = row >> 10, i = row & 1023;
  float acc = cb[d];
#pragma unroll
  for (int j = 0; j < 3; ++j) {
    int t = i + j - 2;
    if (t >= 0)
      acc += b2f(x1[((size_t)(b * 1024 + t) << 10) + d]) * cw[d * 3 + j];
  }
  float s = acc / (1.f + expf(-acc));
  xs[((size_t)row << 10) + d] = f2b(s);
}

// ---------- chunked scan: h_t = a_t h_{t-1} + b_t, per (b,d), T=1024, chunks of 64 ----------
__global__ void k_scan1(const float* __restrict__ Abar, const unsigned short* __restrict__ Bx,
                        float* __restrict__ cA, float* __restrict__ cB) {
  const int g = blockIdx.x * 256 + threadIdx.x;   // 8*16*1024
  const int d = g & 1023, bc = g >> 10;
  const int b = bc >> 4, c = bc & 15;
  size_t base = ((size_t)(b * 1024 + c * 64) << 10) + d;
  float aA = 1.f, aB = 0.f;
  for (int t = 0; t < 64; ++t) {
    float a = Abar[base], bx = b2f(Bx[base]);
    aA *= a; aB = a * aB + bx; base += 1024;
  }
  cA[g] = aA; cB[g] = aB;
}
__global__ void k_scan2(const float* __restrict__ cA, const float* __restrict__ cB,
                        float* __restrict__ carry) {
  const int g = blockIdx.x * 256 + threadIdx.x;   // 8192
  const int d = g & 1023, b = g >> 10;
  float sB = 0.f;
  for (int c = 0; c < 16; ++c) {
    int idx = ((b * 16 + c) << 10) + d;
    carry[idx] = sB;
    sB = cA[idx] * sB + cB[idx];
  }
}
__global__ void k_scan3(const float* __restrict__ Abar, const unsigned short* __restrict__ Bx,
                        const float* __restrict__ carry, unsigned short* __restrict__ hb) {
  const int g = blockIdx.x * 256 + threadIdx.x;
  const int d = g & 1023, bc = g >> 10;
  const int b = bc >> 4, c = bc & 15;
  size_t base = ((size_t)(b * 1024 + c * 64) << 10) + d;
  float h = carry[g];
  for (int t = 0; t < 64; ++t) {
    float a = Abar[base], bx = b2f(Bx[base]);
    h = a * h + bx;
    hb[base] = f2b(h);
    base += 1024;
  }
}

// ---------- transpose x_res per batch: [b][m][n] -> [b][n][m] (bf16) ----------
__global__ void k_transpose_xres(const unsigned short* __restrict__ src,
                                 unsigned short* __restrict__ dst) {
  __shared__ unsigned short tile[32][33];
  const int b = blockIdx.z;
  const int bx = blockIdx.x << 5, by = blockIdx.y << 5;
  const int tx = threadIdx.x, ty = threadIdx.y;   // 32 x 8
  const unsigned short* s = src + ((size_t)b << 20);
  unsigned short* d = dst + ((size_t)b << 20);
#pragma unroll
  for (int i = 0; i < 4; ++i)
    tile[ty + i * 8][tx] = s[(size_t)(by + ty + i * 8) * 1024 + bx + tx];
  __syncthreads();
#pragma unroll
  for (int i = 0; i < 4; ++i)
    d[(size_t)(bx + ty + i * 8) * 1024 + by + tx] = tile[tx][ty + i * 8];
}

// ---------- GEMM: C[8192x1024] = A[8192x1024](bf16) * Bt[1024x1024]^T(bf16) ----------
// 128x128 block tile, BK=64, 4 waves (2x2), 16x16x32 bf16 MFMA, global_load_lds(16B).
// EPI: 0 = bf16 store; 1 = A_bar = exp(-softplus(v+aux1[col]) * aux2[col]) f32;
//      2 = bf16(v + aux1[col]); 3 = bf16(v + aux1[col] + bf16 aux2[idx]);
//      4 = bf16(silu(v)); 5 = f32 store.
template <int EPI, bool BATCHB>
__global__ __launch_bounds__(256)
void k_gemm(const unsigned short* __restrict__ A, const unsigned short* __restrict__ Bt,
            void* __restrict__ outp, const float* __restrict__ aux1,
            const void* __restrict__ aux2) {
  __shared__ unsigned short As[128 * 64];
  __shared__ unsigned short Bs[128 * 64];
  const int tid = threadIdx.x;
  const int m0 = blockIdx.y << 7;
  const int n0 = blockIdx.x << 7;
  const int wid = tid >> 6, l = tid & 63;
  const int wr = ((wid >> 1) << 6);   // wave row offset: 0 / 64
  const int wc = ((wid & 1) << 6);    // wave col offset: 0 / 64
  const int lr = l & 15, kg = l >> 4;
  if (BATCHB) Bt += (size_t)(m0 >> 10) << 20;   // per-batch B (1024x1024 each)

  f32x4 acc[4][4];
#pragma unroll
  for (int i = 0; i < 4; ++i)
#pragma unroll
    for (int j = 0; j < 4; ++j) acc[i][j] = (f32x4){0.f, 0.f, 0.f, 0.f};

  const int frow = tid >> 3;            // 0..31
  const int fcol = (tid & 7) << 3;      // 0..56
  const size_t aBase = (size_t)(m0 + frow) * 1024 + fcol;
  const size_t bBase = (size_t)(n0 + frow) * 1024 + fcol;
  unsigned short* AsW = &As[tid << 3];
  unsigned short* BsW = &Bs[tid << 3];

  for (int k0 = 0; k0 < 1024; k0 += 64) {
#pragma unroll
    for (int it = 0; it < 4; ++it)
      async_copy16(A + aBase + (size_t)(it * 32) * 1024 + k0, AsW + it * 2048);
#pragma unroll
    for (int it = 0; it < 4; ++it)
      async_copy16(Bt + bBase + (size_t)(it * 32) * 1024 + k0, BsW + it * 2048);
    __syncthreads();   // drains vmcnt -> staged tile visible
#pragma unroll
    for (int ks = 0; ks < 2; ++ks) {
      bf16x8 aF[4], bF[4];
#pragma unroll
      for (int mi = 0; mi < 4; ++mi)
        aF[mi] = *(const bf16x8*)&As[((wr + mi * 16 + lr) << 6) + (ks << 5) + (kg << 3)];
#pragma unroll
      for (int ni = 0; ni < 4; ++ni)
        bF[ni] = *(const bf16x8*)&Bs[((wc + ni * 16 + lr) << 6) + (ks << 5) + (kg << 3)];
#pragma unroll
      for (int mi = 0; mi < 4; ++mi)
#pragma unroll
        for (int ni = 0; ni < 4; ++ni)
          acc[mi][ni] = __builtin_amdgcn_mfma_f32_16x16x32_bf16(aF[mi], bF[ni], acc[mi][ni], 0, 0, 0);
    }
    __syncthreads();   // all waves done reading before next stage overwrites
  }

  // epilogue: C/D layout col=lane&15, row=(lane>>4)*4+r  [m89-verified]
#pragma unroll
  for (int mi = 0; mi < 4; ++mi) {
    const int rowb = m0 + wr + mi * 16 + (kg << 2);
#pragma unroll
    for (int ni = 0; ni < 4; ++ni) {
      const int col = n0 + wc + ni * 16 + lr;
#pragma unroll
      for (int r = 0; r < 4; ++r) {
        const int row = rowb + r;
        const size_t idx = ((size_t)row << 10) + col;
        float v = acc[mi][ni][r];
        if (EPI == 0) {
          ((unsigned short*)outp)[idx] = f2b(v);
        } else if (EPI == 1) {
          v += aux1[col];
          float sp = (v > 20.f) ? v : log1pf(expf(v));
          ((float*)outp)[idx] = expf(-sp * ((const float*)aux2)[col]);
        } else if (EPI == 2) {
          ((unsigned short*)outp)[idx] = f2b(v + aux1[col]);
        } else if (EPI == 3) {
          v += aux1[col] + b2f(((const unsigned short*)aux2)[idx]);
          ((unsigned short*)outp)[idx] = f2b(v);
        } else if (EPI == 4) {
          ((unsigned short*)outp)[idx] = f2b(v / (1.f + expf(-v)));
        } else {
          ((float*)outp)[idx] = v;
        }
      }
    }
  }
}

// ---------- launch ----------
extern "C" void kernel_launch(void* const* d_in, const int* in_sizes, int n_in,
                              void* d_out, int out_size, void* d_ws, size_t ws_size,
                              hipStream_t stream) {
  const float* x      = (const float*)d_in[0];
  const float* w1     = (const float*)d_in[1];
  const float* w2     = (const float*)d_in[2];
  const float* w_last = (const float*)d_in[3];
  const float* conv_w = (const float*)d_in[4];
  const float* conv_b = (const float*)d_in[5];
  const float* Avec   = (const float*)d_in[6];
  const float* wB     = (const float*)d_in[7];
  const float* bB     = (const float*)d_in[8];
  const float* wC     = (const float*)d_in[9];
  const float* bC     = (const float*)d_in[10];
  const float* wD     = (const float*)d_in[11];
  const float* bD     = (const float*)d_in[12];
  const float* wdelta = (const float*)d_in[13];
  const float* bdelta = (const float*)d_in[14];

  char* ws = (char*)d_ws;
  const size_t MB = 1ull << 20;
  const size_t NW = 1ull << 20;   // elements per weight slot (1024*1024)
  // slots: 0 w1T, 1 wdeltaT, 2 wBT, 3 wDT, 4 wCT, 5 w2T, 6 w_lastT
  unsigned short* wT   = (unsigned short*)(ws);             // 14MB
  unsigned short* xb   = (unsigned short*)(ws + 14 * MB);   // 16MB; later: ssm
  unsigned short* x1   = (unsigned short*)(ws + 30 * MB);   // 16MB; later: x_res
  unsigned short* xs   = (unsigned short*)(ws + 46 * MB);   // 16MB; later: hb
  float*          Abar = (float*)(ws + 62 * MB);            // 32MB; later: x_resT + z
  unsigned short* Bx   = (unsigned short*)(ws + 94 * MB);   // 16MB
  unsigned short* xD   = (unsigned short*)(ws + 110 * MB);  // 16MB
  float*          cA   = (float*)(ws + 126 * MB);           // 512KB
  float*          cB   = (float*)(ws + 126 * MB + 512 * 1024);
  float*          carry= (float*)(ws + 127 * MB);           // 512KB
  unsigned short* hb    = xs;                                // reuse
  unsigned short* ssm   = xb;                                // reuse
  unsigned short* xres  = x1;                                // reuse
  unsigned short* xresT = (unsigned short*)(ws + 62 * MB);   // reuse Abar[0:16MB]
  unsigned short* z     = (unsigned short*)(ws + 78 * MB);   // reuse Abar[16:32MB]

  dim3 bT(32, 8);
  dim3 gG(8, 64);   // N/128 x M/128

  k_prep_w<<<dim3(32, 32, 7), bT, 0, stream>>>(w1, wdelta, wB, wD, wC, w2, w_last, wT);
  k_cast_x<<<8192, 256, 0, stream>>>(x, xb);
  // x1 = xb @ w1
  k_gemm<0, false><<<gG, 256, 0, stream>>>(xb, wT + 0 * NW, x1, nullptr, nullptr);
  // xs = silu(conv(x1))
  k_conv_silu<<<dim3(8192, 4), 256, 0, stream>>>(x1, conv_w, conv_b, xs);
  // A_bar = exp(-softplus(xs@wdelta + bdelta) * A)   (f32)
  k_gemm<1, false><<<gG, 256, 0, stream>>>(xs, wT + 1 * NW, Abar, bdelta, Avec);
  // Bx = xs@wB + bB   (bf16)
  k_gemm<2, false><<<gG, 256, 0, stream>>>(xs, wT + 2 * NW, Bx, bB, nullptr);
  // xD = xs@wD + bD   (bf16)
  k_gemm<2, false><<<gG, 256, 0, stream>>>(xs, wT + 3 * NW, xD, bD, nullptr);
  // scan -> hb (bf16)
  k_scan1<<<512, 256, 0, stream>>>(Abar, Bx, cA, cB);
  k_scan2<<<32, 256, 0, stream>>>(cA, cB, carry);
  k_scan3<<<512, 256, 0, stream>>>(Abar, Bx, carry, hb);
  // ssm = hb@wC + bC + xD   (bf16)
  k_gemm<3, false><<<gG, 256, 0, stream>>>(hb, wT + 4 * NW, ssm, bC, (const void*)xD);
  // x_res = silu(ssm@w2)   (bf16)
  k_gemm<4, false><<<gG, 256, 0, stream>>>(ssm, wT + 5 * NW, xres, nullptr, nullptr);
  // x_resT per batch
  k_transpose_xres<<<dim3(32, 32, 8), bT, 0, stream>>>(xres, xresT);
  // z = ssm @ x_res (batched via B^T = x_resT)   (bf16)
  k_gemm<0, true><<<gG, 256, 0, stream>>>(ssm, xresT, z, nullptr, nullptr);
  // out = z @ w_last   (f32)
  k_gemm<5, false><<<gG, 256, 0, stream>>>(z, wT + 6 * NW, (float*)d_out, nullptr, nullptr);
}

// Round 2
// 337.591 us; speedup vs baseline: 1.0159x; 1.0159x over previous
//
#include <hip/hip_runtime.h>

// ---------- types / helpers ----------
typedef __bf16 bf16x8 __attribute__((ext_vector_type(8)));
typedef float  f32x4  __attribute__((ext_vector_type(4)));

__device__ __forceinline__ float b2f(unsigned short u) {
  union { float f; unsigned int i; } v; v.i = ((unsigned int)u) << 16; return v.f;
}
__device__ __forceinline__ unsigned short f2b(float f) {
  union { float f; unsigned int i; } v; v.f = f;
  unsigned int r = v.i + 0x7fffu + ((v.i >> 16) & 1u);   // RNE
  return (unsigned short)(r >> 16);
}

__device__ __forceinline__ void async_copy16(const unsigned short* g, unsigned short* l) {
  __builtin_amdgcn_global_load_lds(
      (__attribute__((address_space(1))) void*)g,
      (__attribute__((address_space(3))) void*)l, 16, 0, 0);
}

// ---------- weight prep: transpose+cast 7 f32 [K][N] -> bf16 [N][K] ----------
__global__ void k_prep_w(const float* w0, const float* w1_, const float* w2_,
                         const float* w3_, const float* w4_, const float* w5_,
                         const float* w6_, unsigned short* dst) {
  const float* srcs[7] = {w0, w1_, w2_, w3_, w4_, w5_, w6_};
  const float* src = srcs[blockIdx.z];
  unsigned short* d = dst + ((size_t)blockIdx.z << 20);
  __shared__ float tile[32][33];
  const int bn = blockIdx.x << 5, bk = blockIdx.y << 5;
  const int tx = threadIdx.x, ty = threadIdx.y;   // 32 x 8
#pragma unroll
  for (int i = 0; i < 4; ++i)
    tile[ty + i * 8][tx] = src[(size_t)(bk + ty + i * 8) * 1024 + bn + tx];
  __syncthreads();
#pragma unroll
  for (int i = 0; i < 4; ++i)
    d[(size_t)(bn + ty + i * 8) * 1024 + bk + tx] = f2b(tile[tx][ty + i * 8]);
}

// ---------- cast x [8,1022,1024] f32 -> xb [8,1024,1024] bf16 (rows 1022/1023 zero) ----------
__global__ void k_cast_x(const float* __restrict__ x, unsigned short* __restrict__ xb) {
  const size_t i = ((size_t)blockIdx.x * 256 + threadIdx.x) << 2;
  const int d = (int)(i & 1023);
  const int row = (int)(i >> 10);
  const int t = row & 1023, b = row >> 10;
  float4 v = make_float4(0.f, 0.f, 0.f, 0.f);
  if (t < 1022) v = *(const float4*)&x[((size_t)(b * 1022 + t) << 10) + d];
  ushort4 o;
  o.x = f2b(v.x); o.y = f2b(v.y); o.z = f2b(v.z); o.w = f2b(v.w);
  *(ushort4*)&xb[i] = o;
}

// ---------- depthwise conv (k=3) + silu ----------
__global__ void k_conv_silu(const unsigned short* __restrict__ x1, const float* __restrict__ cw,
                            const float* __restrict__ cb, unsigned short* __restrict__ xs) {
  const int d = blockIdx.y * 256 + threadIdx.x;
  const int row = blockIdx.x;              // 0..8191
  const int b = row >> 10, i = row & 1023;
  float acc = cb[d];
#pragma unroll
  for (int j = 0; j < 3; ++j) {
    int t = i + j - 2;
    if (t >= 0)
      acc += b2f(x1[((size_t)(b * 1024 + t) << 10) + d]) * cw[d * 3 + j];
  }
  float s = acc / (1.f + expf(-acc));
  xs[((size_t)row << 10) + d] = f2b(s);
}

// ---------- chunked scan ----------
__global__ void k_scan1(const float* __restrict__ Abar, const unsigned short* __restrict__ Bx,
                        float* __restrict__ cA, float* __restrict__ cB) {
  const int g = blockIdx.x * 256 + threadIdx.x;   // 8*16*1024
  const int d = g & 1023, bc = g >> 10;
  const int b = bc >> 4, c = bc & 15;
  size_t base = ((size_t)(b * 1024 + c * 64) << 10) + d;
  float aA = 1.f, aB = 0.f;
  for (int t = 0; t < 64; ++t) {
    float a = Abar[base], bx = b2f(Bx[base]);
    aA *= a; aB = a * aB + bx; base += 1024;
  }
  cA[g] = aA; cB[g] = aB;
}
__global__ void k_scan2(const float* __restrict__ cA, const float* __restrict__ cB,
                        float* __restrict__ carry) {
  const int g = blockIdx.x * 256 + threadIdx.x;   // 8192
  const int d = g & 1023, b = g >> 10;
  float sB = 0.f;
  for (int c = 0; c < 16; ++c) {
    int idx = ((b * 16 + c) << 10) + d;
    carry[idx] = sB;
    sB = cA[idx] * sB + cB[idx];
  }
}
__global__ void k_scan3(const float* __restrict__ Abar, const unsigned short* __restrict__ Bx,
                        const float* __restrict__ carry, unsigned short* __restrict__ hb) {
  const int g = blockIdx.x * 256 + threadIdx.x;
  const int d = g & 1023, bc = g >> 10;
  const int b = bc >> 4, c = bc & 15;
  size_t base = ((size_t)(b * 1024 + c * 64) << 10) + d;
  float h = carry[g];
  for (int t = 0; t < 64; ++t) {
    float a = Abar[base], bx = b2f(Bx[base]);
    h = a * h + bx;
    hb[base] = f2b(h);
    base += 1024;
  }
}

// ---------- transpose x_res per batch ----------
__global__ void k_transpose_xres(const unsigned short* __restrict__ src,
                                 unsigned short* __restrict__ dst) {
  __shared__ unsigned short tile[32][33];
  const int b = blockIdx.z;
  const int bx = blockIdx.x << 5, by = blockIdx.y << 5;
  const int tx = threadIdx.x, ty = threadIdx.y;   // 32 x 8
  const unsigned short* s = src + ((size_t)b << 20);
  unsigned short* d = dst + ((size_t)b << 20);
#pragma unroll
  for (int i = 0; i < 4; ++i)
    tile[ty + i * 8][tx] = s[(size_t)(by + ty + i * 8) * 1024 + bx + tx];
  __syncthreads();
#pragma unroll
  for (int i = 0; i < 4; ++i)
    d[(size_t)(bx + ty + i * 8) * 1024 + by + tx] = tile[tx][ty + i * 8];
}

// ---------- GEMM: C[8192 x N] = A[8192x1024](bf16) * Bt[N x 1024]^T(bf16) ----------
// 128x128 tile, BK=64, 4 waves, double-buffered LDS (2-phase prefetch pipeline),
// XOR chunk-swizzle (pre-swizzled global source + swizzled ds_read), XCD block swizzle.
// EPI: 0 bf16; 2 bf16(v+aux1[col]); 3 bf16(v+aux1[col]+bf16 aux2[idx]); 4 bf16(silu);
//      5 f32; 6 fused triple {Abar f32 / Bx bf16 / xD bf16} by col segment.
template <int EPI, bool BATCHB>
__global__ __launch_bounds__(256)
void k_gemm(const unsigned short* __restrict__ A, const unsigned short* __restrict__ Bt,
            void* __restrict__ outp, const float* __restrict__ aux1,
            const void* __restrict__ aux2,
            void* __restrict__ out2, void* __restrict__ out3,
            const float* __restrict__ aux3, const float* __restrict__ aux4) {
  __shared__ unsigned short As[2][128 * 64];
  __shared__ unsigned short Bs[2][128 * 64];
  const int tid = threadIdx.x;

  // XCD-aware swizzle (all grids have nwg % 8 == 0): consecutive logical ids -> same XCD
  const int nwg = gridDim.x * gridDim.y;
  int lin = blockIdx.y * gridDim.x + blockIdx.x;
  lin = (lin & 7) * (nwg >> 3) + (lin >> 3);
  const int nxb = gridDim.x;
  const int n0 = (lin % nxb) << 7;
  const int m0 = (lin / nxb) << 7;

  const int wid = tid >> 6, l = tid & 63;
  const int wr = ((wid >> 1) << 6);   // wave row offset: 0 / 64
  const int wc = ((wid & 1) << 6);    // wave col offset: 0 / 64
  const int lr = l & 15, kg = l >> 4;
  const unsigned short* Bp = BATCHB ? Bt + ((size_t)(m0 >> 10) << 20) : Bt;

  f32x4 acc[4][4];
#pragma unroll
  for (int i = 0; i < 4; ++i)
#pragma unroll
    for (int j = 0; j < 4; ++j) acc[i][j] = (f32x4){0.f, 0.f, 0.f, 0.f};

  // staging: thread tid loads 16B; LDS dest linear (tid*16B per it-block);
  // global source column chunk XOR-swizzled so swizzled reads see logical data.
  const int frow = tid >> 3;                                   // 0..31
  const int fchunk = (tid & 7) ^ (frow & 7);                   // pre-swizzled source chunk
  const size_t aBase = (size_t)(m0 + frow) * 1024 + (fchunk << 3);
  const size_t bBase = (size_t)(n0 + frow) * 1024 + (fchunk << 3);

#define STAGE(buf, k0)                                                          \
  {                                                                             \
    _Pragma("unroll")                                                           \
    for (int it = 0; it < 4; ++it)                                              \
      async_copy16(A + aBase + (size_t)(it * 32) * 1024 + (k0),                 \
                   &As[buf][(tid << 3) + it * 2048]);                           \
    _Pragma("unroll")                                                           \
    for (int it = 0; it < 4; ++it)                                              \
      async_copy16(Bp + bBase + (size_t)(it * 32) * 1024 + (k0),                \
                   &Bs[buf][(tid << 3) + it * 2048]);                           \
  }

  STAGE(0, 0);
  __syncthreads();   // prologue drain (vmcnt0 + barrier)

  for (int k0 = 0; k0 < 1024; k0 += 64) {
    const int cur = (k0 >> 6) & 1;
    if (k0 + 64 < 1024) STAGE(cur ^ 1, k0 + 64);   // issue next tile, do NOT wait
#pragma unroll
    for (int ks = 0; ks < 2; ++ks) {
      bf16x8 aF[4], bF[4];
#pragma unroll
      for (int mi = 0; mi < 4; ++mi) {
        const int row = wr + mi * 16 + lr;
        aF[mi] = *(const bf16x8*)&As[cur][(row << 6) + (((ks * 4 + kg) ^ (lr & 7)) << 3)];
      }
#pragma unroll
      for (int ni = 0; ni < 4; ++ni) {
        const int row = wc + ni * 16 + lr;
        bF[ni] = *(const bf16x8*)&Bs[cur][(row << 6) + (((ks * 4 + kg) ^ (lr & 7)) << 3)];
      }
#pragma unroll
      for (int mi = 0; mi < 4; ++mi)
#pragma unroll
        for (int ni = 0; ni < 4; ++ni)
          acc[mi][ni] = __builtin_amdgcn_mfma_f32_16x16x32_bf16(aF[mi], bF[ni], acc[mi][ni], 0, 0, 0);
    }
    __syncthreads();   // drains vmcnt(0)+lgkmcnt(0): next tile landed, all reads done
  }
#undef STAGE

  // epilogue: C/D layout col=lane&15, row=(lane>>4)*4+r  [m89-verified]
#pragma unroll
  for (int mi = 0; mi < 4; ++mi) {
    const int rowb = m0 + wr + mi * 16 + (kg << 2);
#pragma unroll
    for (int ni = 0; ni < 4; ++ni) {
      const int col = n0 + wc + ni * 16 + lr;
#pragma unroll
      for (int r = 0; r < 4; ++r) {
        const int row = rowb + r;
        const size_t idx = ((size_t)row << 10) + col;
        float v = acc[mi][ni][r];
        if (EPI == 0) {
          ((unsigned short*)outp)[idx] = f2b(v);
        } else if (EPI == 2) {
          ((unsigned short*)outp)[idx] = f2b(v + aux1[col]);
        } else if (EPI == 3) {
          v += aux1[col] + b2f(((const unsigned short*)aux2)[idx]);
          ((unsigned short*)outp)[idx] = f2b(v);
        } else if (EPI == 4) {
          ((unsigned short*)outp)[idx] = f2b(v / (1.f + expf(-v)));
        } else if (EPI == 5) {
          ((float*)outp)[idx] = v;
        } else {  // EPI 6: fused {A_bar | Bx | xD}, segment uniform per block
          const int seg = n0 >> 10;
          const int c1 = col & 1023;
          const size_t idx2 = ((size_t)row << 10) + c1;
          if (seg == 0) {
            float v2 = v + aux1[c1];                     // + bdelta
            float sp = (v2 > 20.f) ? v2 : log1pf(expf(v2));
            ((float*)outp)[idx2] = expf(-sp * ((const float*)aux2)[c1]);   // A_bar
          } else if (seg == 1) {
            ((unsigned short*)out2)[idx2] = f2b(v + aux3[c1]);             // Bx + bB
          } else {
            ((unsigned short*)out3)[idx2] = f2b(v + aux4[c1]);             // xD + bD
          }
        }
      }
    }
  }
}

// ---------- launch ----------
extern "C" void kernel_launch(void* const* d_in, const int* in_sizes, int n_in,
                              void* d_out, int out_size, void* d_ws, size_t ws_size,
                              hipStream_t stream) {
  const float* x      = (const float*)d_in[0];
  const float* w1     = (const float*)d_in[1];
  const float* w2     = (const float*)d_in[2];
  const float* w_last = (const float*)d_in[3];
  const float* conv_w = (const float*)d_in[4];
  const float* conv_b = (const float*)d_in[5];
  const float* Avec   = (const float*)d_in[6];
  const float* wB     = (const float*)d_in[7];
  const float* bB     = (const float*)d_in[8];
  const float* wC     = (const float*)d_in[9];
  const float* bC     = (const float*)d_in[10];
  const float* wD     = (const float*)d_in[11];
  const float* bD     = (const float*)d_in[12];
  const float* wdelta = (const float*)d_in[13];
  const float* bdelta = (const float*)d_in[14];

  char* ws = (char*)d_ws;
  const size_t MB = 1ull << 20;
  const size_t NW = 1ull << 20;   // elements per weight slot (1024*1024)
  // slots: 0 w1T, 1 wdeltaT, 2 wBT, 3 wDT, 4 wCT, 5 w2T, 6 w_lastT  (1-3 fused as N=3072)
  unsigned short* wT   = (unsigned short*)(ws);             // 14MB
  unsigned short* xb   = (unsigned short*)(ws + 14 * MB);   // 16MB; later: ssm
  unsigned short* x1   = (unsigned short*)(ws + 30 * MB);   // 16MB; later: x_res
  unsigned short* xs   = (unsigned short*)(ws + 46 * MB);   // 16MB; later: hb
  float*          Abar = (float*)(ws + 62 * MB);            // 32MB; later: x_resT + z
  unsigned short* Bx   = (unsigned short*)(ws + 94 * MB);   // 16MB
  unsigned short* xD   = (unsigned short*)(ws + 110 * MB);  // 16MB
  float*          cA   = (float*)(ws + 126 * MB);           // 512KB
  float*          cB   = (float*)(ws + 126 * MB + 512 * 1024);
  float*          carry= (float*)(ws + 127 * MB);           // 512KB
  unsigned short* hb    = xs;                                // reuse
  unsigned short* ssm   = xb;                                // reuse
  unsigned short* xres  = x1;                                // reuse
  unsigned short* xresT = (unsigned short*)(ws + 62 * MB);   // reuse Abar[0:16MB]
  unsigned short* z     = (unsigned short*)(ws + 78 * MB);   // reuse Abar[16:32MB]

  dim3 bT(32, 8);
  dim3 gG(8, 64);    // N/128 x M/128 (nwg=512, %8==0)
  dim3 gF(24, 64);   // fused N=3072  (nwg=1536, %8==0)

  k_prep_w<<<dim3(32, 32, 7), bT, 0, stream>>>(w1, wdelta, wB, wD, wC, w2, w_last, wT);
  k_cast_x<<<8192, 256, 0, stream>>>(x, xb);
  // x1 = xb @ w1
  k_gemm<0, false><<<gG, 256, 0, stream>>>(xb, wT + 0 * NW, x1, nullptr, nullptr,
                                           nullptr, nullptr, nullptr, nullptr);
  // xs = silu(conv(x1))
  k_conv_silu<<<dim3(8192, 4), 256, 0, stream>>>(x1, conv_w, conv_b, xs);
  // fused: A_bar (f32), Bx (bf16), xD (bf16) from xs @ [wdelta|wB|wD]
  k_gemm<6, false><<<gF, 256, 0, stream>>>(xs, wT + 1 * NW, Abar, bdelta, (const void*)Avec,
                                           Bx, xD, bB, bD);
  // scan -> hb (bf16)
  k_scan1<<<512, 256, 0, stream>>>(Abar, Bx, cA, cB);
  k_scan2<<<32, 256, 0, stream>>>(cA, cB, carry);
  k_scan3<<<512, 256, 0, stream>>>(Abar, Bx, carry, hb);
  // ssm = hb@wC + bC + xD
  k_gemm<3, false><<<gG, 256, 0, stream>>>(hb, wT + 4 * NW, ssm, bC, (const void*)xD,
                                           nullptr, nullptr, nullptr, nullptr);
  // x_res = silu(ssm@w2)
  k_gemm<4, false><<<gG, 256, 0, stream>>>(ssm, wT + 5 * NW, xres, nullptr, nullptr,
                                           nullptr, nullptr, nullptr, nullptr);
  // x_resT per batch
  k_transpose_xres<<<dim3(32, 32, 8), bT, 0, stream>>>(xres, xresT);
  // z = ssm @ x_res (batched via B^T = x_resT)
  k_gemm<0, true><<<gG, 256, 0, stream>>>(ssm, xresT, z, nullptr, nullptr,
                                          nullptr, nullptr, nullptr, nullptr);
  // out = z @ w_last (f32)
  k_gemm<5, false><<<gG, 256, 0, stream>>>(z, wT + 6 * NW, (float*)d_out, nullptr, nullptr,
                                           nullptr, nullptr, nullptr, nullptr);
}

// Round 3
// 292.593 us; speedup vs baseline: 1.1722x; 1.1538x over previous
//
#include <hip/hip_runtime.h>

// ---------- types / helpers ----------
typedef __bf16 bf16x8 __attribute__((ext_vector_type(8)));
typedef float  f32x4  __attribute__((ext_vector_type(4)));
typedef unsigned short u16x8 __attribute__((ext_vector_type(8)));

__device__ __forceinline__ float b2f(unsigned short u) {
  union { float f; unsigned int i; } v; v.i = ((unsigned int)u) << 16; return v.f;
}
__device__ __forceinline__ unsigned short f2b(float f) {
  union { float f; unsigned int i; } v; v.f = f;
  unsigned int r = v.i + 0x7fffu + ((v.i >> 16) & 1u);   // RNE
  return (unsigned short)(r >> 16);
}

__device__ __forceinline__ void async_copy16(const unsigned short* g, unsigned short* l) {
  __builtin_amdgcn_global_load_lds(
      (__attribute__((address_space(1))) void*)g,
      (__attribute__((address_space(3))) void*)l, 16, 0, 0);
}

// ---------- weight prep: transpose+cast 7 f32 [K][N] -> bf16 [N][K] ----------
__global__ void k_prep_w(const float* w0, const float* w1_, const float* w2_,
                         const float* w3_, const float* w4_, const float* w5_,
                         const float* w6_, unsigned short* dst) {
  const float* srcs[7] = {w0, w1_, w2_, w3_, w4_, w5_, w6_};
  const float* src = srcs[blockIdx.z];
  unsigned short* d = dst + ((size_t)blockIdx.z << 20);
  __shared__ float tile[32][33];
  const int bn = blockIdx.x << 5, bk = blockIdx.y << 5;
  const int tx = threadIdx.x, ty = threadIdx.y;   // 32 x 8
#pragma unroll
  for (int i = 0; i < 4; ++i)
    tile[ty + i * 8][tx] = src[(size_t)(bk + ty + i * 8) * 1024 + bn + tx];
  __syncthreads();
#pragma unroll
  for (int i = 0; i < 4; ++i)
    d[(size_t)(bn + ty + i * 8) * 1024 + bk + tx] = f2b(tile[tx][ty + i * 8]);
}

// ---------- conv weight transpose: cwT[j*1024+d] = conv_w[d*3+j] ----------
__global__ void k_prep_cw(const float* __restrict__ cw, float* __restrict__ cwT) {
  const int idx = blockIdx.x * 256 + threadIdx.x;   // 3072
  const int d = idx & 1023, j = idx >> 10;
  cwT[idx] = cw[d * 3 + j];
}

// ---------- cast x [8,1022,1024] f32 -> xb [8,1024,1024] bf16 (rows 1022/1023 zero) ----------
__global__ void k_cast_x(const float* __restrict__ x, unsigned short* __restrict__ xb) {
  const size_t i = ((size_t)blockIdx.x * 256 + threadIdx.x) << 2;
  const int d = (int)(i & 1023);
  const int row = (int)(i >> 10);
  const int t = row & 1023, b = row >> 10;
  float4 v = make_float4(0.f, 0.f, 0.f, 0.f);
  if (t < 1022) v = *(const float4*)&x[((size_t)(b * 1022 + t) << 10) + d];
  ushort4 o;
  o.x = f2b(v.x); o.y = f2b(v.y); o.z = f2b(v.z); o.w = f2b(v.w);
  *(ushort4*)&xb[i] = o;
}

// ---------- depthwise conv (k=3) + silu, vectorized x8 ----------
__global__ void k_conv_silu(const unsigned short* __restrict__ x1, const float* __restrict__ cwT,
                            const float* __restrict__ cb, unsigned short* __restrict__ xs) {
  const int gid = blockIdx.x * 256 + threadIdx.x;   // 8192 rows * 128 thr
  const int row = gid >> 7;
  const int d0 = (gid & 127) << 3;
  const int b = row >> 10, i = row & 1023;
  float acc[8];
  {
    float4 c0 = *(const float4*)&cb[d0], c1 = *(const float4*)&cb[d0 + 4];
    acc[0] = c0.x; acc[1] = c0.y; acc[2] = c0.z; acc[3] = c0.w;
    acc[4] = c1.x; acc[5] = c1.y; acc[6] = c1.z; acc[7] = c1.w;
  }
#pragma unroll
  for (int j = 0; j < 3; ++j) {
    const int t = i + j - 2;
    if (t >= 0) {
      u16x8 v = *(const u16x8*)&x1[((size_t)(b * 1024 + t) << 10) + d0];
      float4 w0 = *(const float4*)&cwT[j * 1024 + d0];
      float4 w1 = *(const float4*)&cwT[j * 1024 + d0 + 4];
      acc[0] += b2f(v[0]) * w0.x; acc[1] += b2f(v[1]) * w0.y;
      acc[2] += b2f(v[2]) * w0.z; acc[3] += b2f(v[3]) * w0.w;
      acc[4] += b2f(v[4]) * w1.x; acc[5] += b2f(v[5]) * w1.y;
      acc[6] += b2f(v[6]) * w1.z; acc[7] += b2f(v[7]) * w1.w;
    }
  }
  u16x8 o;
#pragma unroll
  for (int k = 0; k < 8; ++k) {
    float s = acc[k] / (1.f + expf(-acc[k]));
    o[k] = f2b(s);
  }
  *(u16x8*)&xs[((size_t)row << 10) + d0] = o;
}

// ---------- chunked scan ----------
__global__ void k_scan1(const float* __restrict__ Abar, const unsigned short* __restrict__ Bx,
                        float* __restrict__ cA, float* __restrict__ cB) {
  const int g = blockIdx.x * 256 + threadIdx.x;   // 8*16*1024
  const int d = g & 1023, bc = g >> 10;
  const int b = bc >> 4, c = bc & 15;
  size_t base = ((size_t)(b * 1024 + c * 64) << 10) + d;
  float aA = 1.f, aB = 0.f;
  for (int t = 0; t < 64; ++t) {
    float a = Abar[base], bx = b2f(Bx[base]);
    aA *= a; aB = a * aB + bx; base += 1024;
  }
  cA[g] = aA; cB[g] = aB;
}
__global__ void k_scan2(const float* __restrict__ cA, const float* __restrict__ cB,
                        float* __restrict__ carry) {
  const int g = blockIdx.x * 256 + threadIdx.x;   // 8192
  const int d = g & 1023, b = g >> 10;
  float a[16], bb[16];
#pragma unroll
  for (int c = 0; c < 16; ++c) {
    const int idx = ((b * 16 + c) << 10) + d;
    a[c] = cA[idx]; bb[c] = cB[idx];
  }
  float sB = 0.f;
#pragma unroll
  for (int c = 0; c < 16; ++c) {
    carry[((b * 16 + c) << 10) + d] = sB;
    sB = a[c] * sB + bb[c];
  }
}
__global__ void k_scan3(const float* __restrict__ Abar, const unsigned short* __restrict__ Bx,
                        const float* __restrict__ carry, unsigned short* __restrict__ hb) {
  const int g = blockIdx.x * 256 + threadIdx.x;
  const int d = g & 1023, bc = g >> 10;
  const int b = bc >> 4, c = bc & 15;
  size_t base = ((size_t)(b * 1024 + c * 64) << 10) + d;
  float h = carry[g];
  for (int t = 0; t < 64; ++t) {
    float a = Abar[base], bx = b2f(Bx[base]);
    h = a * h + bx;
    hb[base] = f2b(h);
    base += 1024;
  }
}

// ---------- transpose x_res per batch ----------
__global__ void k_transpose_xres(const unsigned short* __restrict__ src,
                                 unsigned short* __restrict__ dst) {
  __shared__ unsigned short tile[32][33];
  const int b = blockIdx.z;
  const int bx = blockIdx.x << 5, by = blockIdx.y << 5;
  const int tx = threadIdx.x, ty = threadIdx.y;   // 32 x 8
  const unsigned short* s = src + ((size_t)b << 20);
  unsigned short* d = dst + ((size_t)b << 20);
#pragma unroll
  for (int i = 0; i < 4; ++i)
    tile[ty + i * 8][tx] = s[(size_t)(by + ty + i * 8) * 1024 + bx + tx];
  __syncthreads();
#pragma unroll
  for (int i = 0; i < 4; ++i)
    d[(size_t)(bx + ty + i * 8) * 1024 + by + tx] = tile[tx][ty + i * 8];
}

// ---------- GEMM: C[8192 x N] = A[8192x1024](bf16) * Bt[N x 1024]^T(bf16) ----------
// 128x128 tile, BK=64, 4 waves. TRUE 2-deep pipeline: counted s_waitcnt vmcnt(8),
// raw s_barriers (never drain vmcnt mid-loop). XOR chunk swizzle (0 conflicts).
// Block order: XCD chunk -> 8-m-block groups, m fastest (B-tile + A-group L2-resident).
template <int EPI, bool BATCHB>
__global__ __launch_bounds__(256)
void k_gemm(const unsigned short* __restrict__ A, const unsigned short* __restrict__ Bt,
            void* __restrict__ outp, const float* __restrict__ aux1,
            const void* __restrict__ aux2,
            void* __restrict__ out2, void* __restrict__ out3,
            const float* __restrict__ aux3, const float* __restrict__ aux4) {
  __shared__ unsigned short As[2][128 * 64];
  __shared__ unsigned short Bs[2][128 * 64];
  const int tid = threadIdx.x;

  // XCD chunking + m-fastest order inside 8-m-block groups
  const int nxb = gridDim.x;            // n-blocks
  const int nwg = nxb * gridDim.y;
  int lin = blockIdx.y * nxb + blockIdx.x;
  lin = (lin & 7) * (nwg >> 3) + (lin >> 3);
  const int CH = nxb << 3;              // 8 m-blocks x all n
  const int grp = lin / CH, idx = lin % CH;
  const int m0 = ((grp << 3) + (idx & 7)) << 7;
  const int n0 = (idx >> 3) << 7;

  const int wid = tid >> 6, l = tid & 63;
  const int wr = ((wid >> 1) << 6);
  const int wc = ((wid & 1) << 6);
  const int lr = l & 15, kg = l >> 4;
  const unsigned short* Bp = BATCHB ? Bt + ((size_t)(m0 >> 10) << 20) : Bt;

  f32x4 acc[4][4];
#pragma unroll
  for (int i = 0; i < 4; ++i)
#pragma unroll
    for (int j = 0; j < 4; ++j) acc[i][j] = (f32x4){0.f, 0.f, 0.f, 0.f};

  // staging: 16B/thread/it-block; LDS dest linear; global source chunk XOR-pre-swizzled
  const int frow = tid >> 3;
  const int fchunk = (tid & 7) ^ (frow & 7);
  const size_t aBase = (size_t)(m0 + frow) * 1024 + (fchunk << 3);
  const size_t bBase = (size_t)(n0 + frow) * 1024 + (fchunk << 3);

#define STAGE(buf, k0)                                                          \
  {                                                                             \
    _Pragma("unroll")                                                           \
    for (int it = 0; it < 4; ++it)                                              \
      async_copy16(A + aBase + (size_t)(it * 32) * 1024 + (k0),                 \
                   &As[buf][(tid << 3) + it * 2048]);                           \
    _Pragma("unroll")                                                           \
    for (int it = 0; it < 4; ++it)                                              \
      async_copy16(Bp + bBase + (size_t)(it * 32) * 1024 + (k0),                \
                   &Bs[buf][(tid << 3) + it * 2048]);                           \
  }

  STAGE(0, 0);
  STAGE(1, 64);   // 16 loads/thread in flight

#pragma unroll
  for (int t = 0; t < 16; ++t) {
    const int cur = t & 1;
    if (t < 15) asm volatile("s_waitcnt vmcnt(8)" ::: "memory");  // tile t landed, t+1 in flight
    else        asm volatile("s_waitcnt vmcnt(0)" ::: "memory");
    __builtin_amdgcn_s_barrier();       // all threads' tile-t loads in LDS
    __builtin_amdgcn_sched_barrier(0);
#pragma unroll
    for (int ks = 0; ks < 2; ++ks) {
      bf16x8 aF[4], bF[4];
#pragma unroll
      for (int mi = 0; mi < 4; ++mi) {
        const int row = wr + mi * 16 + lr;
        aF[mi] = *(const bf16x8*)&As[cur][(row << 6) + (((ks * 4 + kg) ^ (lr & 7)) << 3)];
      }
#pragma unroll
      for (int ni = 0; ni < 4; ++ni) {
        const int row = wc + ni * 16 + lr;
        bF[ni] = *(const bf16x8*)&Bs[cur][(row << 6) + (((ks * 4 + kg) ^ (lr & 7)) << 3)];
      }
#pragma unroll
      for (int mi = 0; mi < 4; ++mi)
#pragma unroll
        for (int ni = 0; ni < 4; ++ni)
          acc[mi][ni] = __builtin_amdgcn_mfma_f32_16x16x32_bf16(aF[mi], bF[ni], acc[mi][ni], 0, 0, 0);
    }
    asm volatile("s_waitcnt lgkmcnt(0)" ::: "memory");   // LDS reads of buf cur complete
    __builtin_amdgcn_s_barrier();       // all waves done with buf cur
    __builtin_amdgcn_sched_barrier(0);
    if (t + 2 < 16) STAGE(cur, (t + 2) * 64);   // overwrite buf cur with tile t+2
  }
#undef STAGE

  // epilogue: C/D layout col=lane&15, row=(lane>>4)*4+r
#pragma unroll
  for (int mi = 0; mi < 4; ++mi) {
    const int rowb = m0 + wr + mi * 16 + (kg << 2);
#pragma unroll
    for (int ni = 0; ni < 4; ++ni) {
      const int col = n0 + wc + ni * 16 + lr;
#pragma unroll
      for (int r = 0; r < 4; ++r) {
        const int row = rowb + r;
        const size_t idx2 = ((size_t)row << 10) + col;
        float v = acc[mi][ni][r];
        if (EPI == 0) {
          ((unsigned short*)outp)[idx2] = f2b(v);
        } else if (EPI == 3) {
          v += aux1[col] + b2f(((const unsigned short*)aux2)[idx2]);
          ((unsigned short*)outp)[idx2] = f2b(v);
        } else if (EPI == 4) {
          ((unsigned short*)outp)[idx2] = f2b(v / (1.f + expf(-v)));
        } else if (EPI == 5) {
          ((float*)outp)[idx2] = v;
        } else {  // EPI 6: fused {A_bar | Bx | xD}, segment uniform per block
          const int seg = n0 >> 10;
          const int c1 = col & 1023;
          const size_t idx3 = ((size_t)row << 10) + c1;
          if (seg == 0) {
            float v2 = v + aux1[c1];                     // + bdelta
            float sp = (v2 > 20.f) ? v2 : log1pf(expf(v2));
            ((float*)outp)[idx3] = expf(-sp * ((const float*)aux2)[c1]);   // A_bar
          } else if (seg == 1) {
            ((unsigned short*)out2)[idx3] = f2b(v + aux3[c1]);             // Bx + bB
          } else {
            ((unsigned short*)out3)[idx3] = f2b(v + aux4[c1]);             // xD + bD
          }
        }
      }
    }
  }
}

// ---------- launch ----------
extern "C" void kernel_launch(void* const* d_in, const int* in_sizes, int n_in,
                              void* d_out, int out_size, void* d_ws, size_t ws_size,
                              hipStream_t stream) {
  const float* x      = (const float*)d_in[0];
  const float* w1     = (const float*)d_in[1];
  const float* w2     = (const float*)d_in[2];
  const float* w_last = (const float*)d_in[3];
  const float* conv_w = (const float*)d_in[4];
  const float* conv_b = (const float*)d_in[5];
  const float* Avec   = (const float*)d_in[6];
  const float* wB     = (const float*)d_in[7];
  const float* bB     = (const float*)d_in[8];
  const float* wC     = (const float*)d_in[9];
  const float* bC     = (const float*)d_in[10];
  const float* wD     = (const float*)d_in[11];
  const float* bD     = (const float*)d_in[12];
  const float* wdelta = (const float*)d_in[13];
  const float* bdelta = (const float*)d_in[14];

  char* ws = (char*)d_ws;
  const size_t MB = 1ull << 20;
  const size_t NW = 1ull << 20;
  unsigned short* wT   = (unsigned short*)(ws);             // 14MB
  unsigned short* xb   = (unsigned short*)(ws + 14 * MB);   // 16MB; later: ssm
  unsigned short* x1   = (unsigned short*)(ws + 30 * MB);   // 16MB; later: x_res
  unsigned short* xs   = (unsigned short*)(ws + 46 * MB);   // 16MB; later: hb
  float*          Abar = (float*)(ws + 62 * MB);            // 32MB; later: x_resT + z
  unsigned short* Bx   = (unsigned short*)(ws + 94 * MB);   // 16MB
  unsigned short* xD   = (unsigned short*)(ws + 110 * MB);  // 16MB
  float*          cA   = (float*)(ws + 126 * MB);
  float*          cB   = (float*)(ws + 126 * MB + 512 * 1024);
  float*          carry= (float*)(ws + 127 * MB);
  float*          cwT  = (float*)(ws + 127 * MB + 512 * 1024);  // 12KB
  unsigned short* hb    = xs;
  unsigned short* ssm   = xb;
  unsigned short* xres  = x1;
  unsigned short* xresT = (unsigned short*)(ws + 62 * MB);
  unsigned short* z     = (unsigned short*)(ws + 78 * MB);

  dim3 bT(32, 8);
  dim3 gG(8, 64);    // nwg=512
  dim3 gF(24, 64);   // nwg=1536

  k_prep_w<<<dim3(32, 32, 7), bT, 0, stream>>>(w1, wdelta, wB, wD, wC, w2, w_last, wT);
  k_prep_cw<<<12, 256, 0, stream>>>(conv_w, cwT);
  k_cast_x<<<8192, 256, 0, stream>>>(x, xb);
  // x1 = xb @ w1
  k_gemm<0, false><<<gG, 256, 0, stream>>>(xb, wT + 0 * NW, x1, nullptr, nullptr,
                                           nullptr, nullptr, nullptr, nullptr);
  // xs = silu(conv(x1))
  k_conv_silu<<<4096, 256, 0, stream>>>(x1, cwT, conv_b, xs);
  // fused: A_bar (f32), Bx (bf16), xD (bf16) from xs @ [wdelta|wB|wD]
  k_gemm<6, false><<<gF, 256, 0, stream>>>(xs, wT + 1 * NW, Abar, bdelta, (const void*)Avec,
                                           Bx, xD, bB, bD);
  // scan -> hb
  k_scan1<<<512, 256, 0, stream>>>(Abar, Bx, cA, cB);
  k_scan2<<<32, 256, 0, stream>>>(cA, cB, carry);
  k_scan3<<<512, 256, 0, stream>>>(Abar, Bx, carry, hb);
  // ssm = hb@wC + bC + xD
  k_gemm<3, false><<<gG, 256, 0, stream>>>(hb, wT + 4 * NW, ssm, bC, (const void*)xD,
                                           nullptr, nullptr, nullptr, nullptr);
  // x_res = silu(ssm@w2)
  k_gemm<4, false><<<gG, 256, 0, stream>>>(ssm, wT + 5 * NW, xres, nullptr, nullptr,
                                           nullptr, nullptr, nullptr, nullptr);
  // x_resT per batch
  k_transpose_xres<<<dim3(32, 32, 8), bT, 0, stream>>>(xres, xresT);
  // z = ssm @ x_res (batched via B^T = x_resT)
  k_gemm<0, true><<<gG, 256, 0, stream>>>(ssm, xresT, z, nullptr, nullptr,
                                          nullptr, nullptr, nullptr, nullptr);
  // out = z @ w_last (f32)
  k_gemm<5, false><<<gG, 256, 0, stream>>>(z, wT + 6 * NW, (float*)d_out, nullptr, nullptr,
                                           nullptr, nullptr, nullptr, nullptr);
}

// Round 4
// 273.159 us; speedup vs baseline: 1.2555x; 1.0711x over previous
//
#include <hip/hip_runtime.h>

// ---------- types / helpers ----------
typedef __bf16 bf16x8 __attribute__((ext_vector_type(8)));
typedef float  f32x4  __attribute__((ext_vector_type(4)));
typedef unsigned short u16x8 __attribute__((ext_vector_type(8)));

__device__ __forceinline__ float b2f(unsigned short u) {
  union { float f; unsigned int i; } v; v.i = ((unsigned int)u) << 16; return v.f;
}
__device__ __forceinline__ unsigned short f2b(float f) {
  union { float f; unsigned int i; } v; v.f = f;
  unsigned int r = v.i + 0x7fffu + ((v.i >> 16) & 1u);   // RNE
  return (unsigned short)(r >> 16);
}

__device__ __forceinline__ void async_copy16(const unsigned short* g, unsigned short* l) {
  __builtin_amdgcn_global_load_lds(
      (__attribute__((address_space(1))) void*)g,
      (__attribute__((address_space(3))) void*)l, 16, 0, 0);
}

// ---------- weight prep: transpose+cast 7 f32 [K][N] -> bf16 [N][K] ----------
__global__ void k_prep_w(const float* w0, const float* w1_, const float* w2_,
                         const float* w3_, const float* w4_, const float* w5_,
                         const float* w6_, unsigned short* dst) {
  const float* srcs[7] = {w0, w1_, w2_, w3_, w4_, w5_, w6_};
  const float* src = srcs[blockIdx.z];
  unsigned short* d = dst + ((size_t)blockIdx.z << 20);
  __shared__ float tile[32][33];
  const int bn = blockIdx.x << 5, bk = blockIdx.y << 5;
  const int tx = threadIdx.x, ty = threadIdx.y;   // 32 x 8
#pragma unroll
  for (int i = 0; i < 4; ++i)
    tile[ty + i * 8][tx] = src[(size_t)(bk + ty + i * 8) * 1024 + bn + tx];
  __syncthreads();
#pragma unroll
  for (int i = 0; i < 4; ++i)
    d[(size_t)(bn + ty + i * 8) * 1024 + bk + tx] = f2b(tile[tx][ty + i * 8]);
}

// ---------- conv weight transpose: cwT[j*1024+d] = conv_w[d*3+j] ----------
__global__ void k_prep_cw(const float* __restrict__ cw, float* __restrict__ cwT) {
  const int idx = blockIdx.x * 256 + threadIdx.x;   // 3072
  const int d = idx & 1023, j = idx >> 10;
  cwT[idx] = cw[d * 3 + j];
}

// ---------- cast x [8,1022,1024] f32 -> xb [8,1024,1024] bf16 (rows 1022/1023 zero) ----------
__global__ void k_cast_x(const float* __restrict__ x, unsigned short* __restrict__ xb) {
  const size_t i = ((size_t)blockIdx.x * 256 + threadIdx.x) << 2;
  const int d = (int)(i & 1023);
  const int row = (int)(i >> 10);
  const int t = row & 1023, b = row >> 10;
  float4 v = make_float4(0.f, 0.f, 0.f, 0.f);
  if (t < 1022) v = *(const float4*)&x[((size_t)(b * 1022 + t) << 10) + d];
  ushort4 o;
  o.x = f2b(v.x); o.y = f2b(v.y); o.z = f2b(v.z); o.w = f2b(v.w);
  *(ushort4*)&xb[i] = o;
}

// ---------- depthwise conv (k=3) + silu, vectorized x8 ----------
__global__ void k_conv_silu(const unsigned short* __restrict__ x1, const float* __restrict__ cwT,
                            const float* __restrict__ cb, unsigned short* __restrict__ xs) {
  const int gid = blockIdx.x * 256 + threadIdx.x;   // 8192 rows * 128 thr
  const int row = gid >> 7;
  const int d0 = (gid & 127) << 3;
  const int b = row >> 10, i = row & 1023;
  float acc[8];
  {
    float4 c0 = *(const float4*)&cb[d0], c1 = *(const float4*)&cb[d0 + 4];
    acc[0] = c0.x; acc[1] = c0.y; acc[2] = c0.z; acc[3] = c0.w;
    acc[4] = c1.x; acc[5] = c1.y; acc[6] = c1.z; acc[7] = c1.w;
  }
#pragma unroll
  for (int j = 0; j < 3; ++j) {
    const int t = i + j - 2;
    if (t >= 0) {
      u16x8 v = *(const u16x8*)&x1[((size_t)(b * 1024 + t) << 10) + d0];
      float4 w0 = *(const float4*)&cwT[j * 1024 + d0];
      float4 w1 = *(const float4*)&cwT[j * 1024 + d0 + 4];
      acc[0] += b2f(v[0]) * w0.x; acc[1] += b2f(v[1]) * w0.y;
      acc[2] += b2f(v[2]) * w0.z; acc[3] += b2f(v[3]) * w0.w;
      acc[4] += b2f(v[4]) * w1.x; acc[5] += b2f(v[5]) * w1.y;
      acc[6] += b2f(v[6]) * w1.z; acc[7] += b2f(v[7]) * w1.w;
    }
  }
  u16x8 o;
#pragma unroll
  for (int k = 0; k < 8; ++k) {
    float s = acc[k] / (1.f + expf(-acc[k]));
    o[k] = f2b(s);
  }
  *(u16x8*)&xs[((size_t)row << 10) + d0] = o;
}

// ---------- chunked scan ----------
__global__ void k_scan1(const float* __restrict__ Abar, const unsigned short* __restrict__ Bx,
                        float* __restrict__ cA, float* __restrict__ cB) {
  const int g = blockIdx.x * 256 + threadIdx.x;   // 8*16*1024
  const int d = g & 1023, bc = g >> 10;
  const int b = bc >> 4, c = bc & 15;
  size_t base = ((size_t)(b * 1024 + c * 64) << 10) + d;
  float aA = 1.f, aB = 0.f;
  for (int t = 0; t < 64; ++t) {
    float a = Abar[base], bx = b2f(Bx[base]);
    aA *= a; aB = a * aB + bx; base += 1024;
  }
  cA[g] = aA; cB[g] = aB;
}
__global__ void k_scan2(const float* __restrict__ cA, const float* __restrict__ cB,
                        float* __restrict__ carry) {
  const int g = blockIdx.x * 256 + threadIdx.x;   // 8192
  const int d = g & 1023, b = g >> 10;
  float a[16], bb[16];
#pragma unroll
  for (int c = 0; c < 16; ++c) {
    const int idx = ((b * 16 + c) << 10) + d;
    a[c] = cA[idx]; bb[c] = cB[idx];
  }
  float sB = 0.f;
#pragma unroll
  for (int c = 0; c < 16; ++c) {
    carry[((b * 16 + c) << 10) + d] = sB;
    sB = a[c] * sB + bb[c];
  }
}
__global__ void k_scan3(const float* __restrict__ Abar, const unsigned short* __restrict__ Bx,
                        const float* __restrict__ carry, unsigned short* __restrict__ hb) {
  const int g = blockIdx.x * 256 + threadIdx.x;
  const int d = g & 1023, bc = g >> 10;
  const int b = bc >> 4, c = bc & 15;
  size_t base = ((size_t)(b * 1024 + c * 64) << 10) + d;
  float h = carry[g];
  for (int t = 0; t < 64; ++t) {
    float a = Abar[base], bx = b2f(Bx[base]);
    h = a * h + bx;
    hb[base] = f2b(h);
    base += 1024;
  }
}

// ---------- transpose x_res per batch ----------
__global__ void k_transpose_xres(const unsigned short* __restrict__ src,
                                 unsigned short* __restrict__ dst) {
  __shared__ unsigned short tile[32][33];
  const int b = blockIdx.z;
  const int bx = blockIdx.x << 5, by = blockIdx.y << 5;
  const int tx = threadIdx.x, ty = threadIdx.y;   // 32 x 8
  const unsigned short* s = src + ((size_t)b << 20);
  unsigned short* d = dst + ((size_t)b << 20);
#pragma unroll
  for (int i = 0; i < 4; ++i)
    tile[ty + i * 8][tx] = s[(size_t)(by + ty + i * 8) * 1024 + bx + tx];
  __syncthreads();
#pragma unroll
  for (int i = 0; i < 4; ++i)
    d[(size_t)(bx + ty + i * 8) * 1024 + by + tx] = tile[tx][ty + i * 8];
}

// ---------- GEMM: C[8192 x 1024] = A[8192x1024](bf16) * Bt[1024 x 1024]^T(bf16) ----------
// 128x128 tile, BK=64, 4 waves. 2-deep counted-vmcnt pipeline (vmcnt(8)), raw barriers.
// XOR chunk swizzle (0 conflicts). Persistent staging pointers (+128B/iter).
// Loop-invariant LDS read offsets (aOff0 / aOff1 = aOff0^64). setprio around MFMA.
// EPI: 0 bf16; 1 A_bar=exp(-softplus(v+aux1[col])*aux2[col]) f32; 2 bf16(v+aux1[col]);
//      3 bf16(v+aux1[col]+bf16 aux2[idx]); 4 bf16(silu(v)); 5 f32.
template <int EPI, bool BATCHB>
__global__ __launch_bounds__(256)
void k_gemm(const unsigned short* __restrict__ A, const unsigned short* __restrict__ Bt,
            void* __restrict__ outp, const float* __restrict__ aux1,
            const void* __restrict__ aux2) {
  __shared__ unsigned short As[2][128 * 64];
  __shared__ unsigned short Bs[2][128 * 64];
  const int tid = threadIdx.x;

  // XCD chunking + m-fastest order inside 8-m-block groups (A-slice 2MB + B 2MB = L2-fit)
  const int nxb = gridDim.x;
  const int nwg = nxb * gridDim.y;
  int lin = blockIdx.y * nxb + blockIdx.x;
  lin = (lin & 7) * (nwg >> 3) + (lin >> 3);
  const int CH = nxb << 3;
  const int grp = lin / CH, idx = lin % CH;
  const int m0 = ((grp << 3) + (idx & 7)) << 7;
  const int n0 = (idx >> 3) << 7;

  const int wid = tid >> 6, l = tid & 63;
  const int wr = ((wid >> 1) << 6);
  const int wc = ((wid & 1) << 6);
  const int lr = l & 15, kg = l >> 4;
  const unsigned short* Bp = BATCHB ? Bt + ((size_t)(m0 >> 10) << 20) : Bt;

  f32x4 acc[4][4];
#pragma unroll
  for (int i = 0; i < 4; ++i)
#pragma unroll
    for (int j = 0; j < 4; ++j) acc[i][j] = (f32x4){0.f, 0.f, 0.f, 0.f};

  // staging: 16B/thread/it-block; LDS dest linear; global source chunk XOR-pre-swizzled.
  // Persistent pointers advanced +64 elems (128B) per staged tile.
  const int frow = tid >> 3;
  const int fchunk = (tid & 7) ^ (frow & 7);
  const unsigned short* ga[4];
  const unsigned short* gb[4];
#pragma unroll
  for (int it = 0; it < 4; ++it) {
    ga[it] = A  + (size_t)(m0 + frow + it * 32) * 1024 + (fchunk << 3);
    gb[it] = Bp + (size_t)(n0 + frow + it * 32) * 1024 + (fchunk << 3);
  }

#define STAGE(buf)                                                              \
  {                                                                             \
    _Pragma("unroll")                                                           \
    for (int it = 0; it < 4; ++it)                                              \
      async_copy16(ga[it], &As[buf][(tid << 3) + it * 2048]);                   \
    _Pragma("unroll")                                                           \
    for (int it = 0; it < 4; ++it)                                              \
      async_copy16(gb[it], &Bs[buf][(tid << 3) + it * 2048]);                   \
    _Pragma("unroll")                                                           \
    for (int it = 0; it < 4; ++it) { ga[it] += 64; gb[it] += 64; }              \
  }

  // loop-invariant LDS read byte-offsets (per 32KB As/Bs array, incl. buffer bit)
  const int c0 = kg ^ (lr & 7);
  const int aOff0 = ((wr + lr) << 7) + (c0 << 4);
  const int aOff1 = aOff0 ^ 64;                      // ks=1 chunk = c0^4
  const int bOff0 = ((wc + lr) << 7) + (c0 << 4);
  const int bOff1 = bOff0 ^ 64;
  const char* AsB = (const char*)&As[0][0];
  const char* BsB = (const char*)&Bs[0][0];

  STAGE(0);
  STAGE(1);   // 16 loads/thread in flight

#pragma unroll
  for (int t = 0; t < 16; ++t) {
    const int cur = t & 1;
    if (t < 15) asm volatile("s_waitcnt vmcnt(8)" ::: "memory");  // tile t landed, t+1 in flight
    else        asm volatile("s_waitcnt vmcnt(0)" ::: "memory");
    __builtin_amdgcn_s_barrier();
    __builtin_amdgcn_sched_barrier(0);
    __builtin_amdgcn_s_setprio(1);
    const char* pa = AsB + (cur << 14);
    const char* pb = BsB + (cur << 14);
    {
      bf16x8 aF[4], bF[4];
#pragma unroll
      for (int mi = 0; mi < 4; ++mi) aF[mi] = *(const bf16x8*)(pa + aOff0 + mi * 2048);
#pragma unroll
      for (int ni = 0; ni < 4; ++ni) bF[ni] = *(const bf16x8*)(pb + bOff0 + ni * 2048);
#pragma unroll
      for (int mi = 0; mi < 4; ++mi)
#pragma unroll
        for (int ni = 0; ni < 4; ++ni)
          acc[mi][ni] = __builtin_amdgcn_mfma_f32_16x16x32_bf16(aF[mi], bF[ni], acc[mi][ni], 0, 0, 0);
    }
    {
      bf16x8 aF[4], bF[4];
#pragma unroll
      for (int mi = 0; mi < 4; ++mi) aF[mi] = *(const bf16x8*)(pa + aOff1 + mi * 2048);
#pragma unroll
      for (int ni = 0; ni < 4; ++ni) bF[ni] = *(const bf16x8*)(pb + bOff1 + ni * 2048);
#pragma unroll
      for (int mi = 0; mi < 4; ++mi)
#pragma unroll
        for (int ni = 0; ni < 4; ++ni)
          acc[mi][ni] = __builtin_amdgcn_mfma_f32_16x16x32_bf16(aF[mi], bF[ni], acc[mi][ni], 0, 0, 0);
    }
    __builtin_amdgcn_s_setprio(0);
    asm volatile("s_waitcnt lgkmcnt(0)" ::: "memory");   // LDS reads of buf cur complete
    __builtin_amdgcn_s_barrier();
    __builtin_amdgcn_sched_barrier(0);
    if (t + 2 < 16) STAGE(cur);   // overwrite buf cur with tile t+2
  }
#undef STAGE

  // epilogue: C/D layout col=lane&15, row=(lane>>4)*4+r
#pragma unroll
  for (int mi = 0; mi < 4; ++mi) {
    const int rowb = m0 + wr + mi * 16 + (kg << 2);
#pragma unroll
    for (int ni = 0; ni < 4; ++ni) {
      const int col = n0 + wc + ni * 16 + lr;
#pragma unroll
      for (int r = 0; r < 4; ++r) {
        const int row = rowb + r;
        const size_t idx2 = ((size_t)row << 10) + col;
        float v = acc[mi][ni][r];
        if (EPI == 0) {
          ((unsigned short*)outp)[idx2] = f2b(v);
        } else if (EPI == 1) {
          float v2 = v + aux1[col];
          float sp = (v2 > 20.f) ? v2 : log1pf(expf(v2));
          ((float*)outp)[idx2] = expf(-sp * ((const float*)aux2)[col]);
        } else if (EPI == 2) {
          ((unsigned short*)outp)[idx2] = f2b(v + aux1[col]);
        } else if (EPI == 3) {
          v += aux1[col] + b2f(((const unsigned short*)aux2)[idx2]);
          ((unsigned short*)outp)[idx2] = f2b(v);
        } else if (EPI == 4) {
          ((unsigned short*)outp)[idx2] = f2b(v / (1.f + expf(-v)));
        } else {
          ((float*)outp)[idx2] = v;
        }
      }
    }
  }
}

// ---------- launch ----------
extern "C" void kernel_launch(void* const* d_in, const int* in_sizes, int n_in,
                              void* d_out, int out_size, void* d_ws, size_t ws_size,
                              hipStream_t stream) {
  const float* x      = (const float*)d_in[0];
  const float* w1     = (const float*)d_in[1];
  const float* w2     = (const float*)d_in[2];
  const float* w_last = (const float*)d_in[3];
  const float* conv_w = (const float*)d_in[4];
  const float* conv_b = (const float*)d_in[5];
  const float* Avec   = (const float*)d_in[6];
  const float* wB     = (const float*)d_in[7];
  const float* bB     = (const float*)d_in[8];
  const float* wC     = (const float*)d_in[9];
  const float* bC     = (const float*)d_in[10];
  const float* wD     = (const float*)d_in[11];
  const float* bD     = (const float*)d_in[12];
  const float* wdelta = (const float*)d_in[13];
  const float* bdelta = (const float*)d_in[14];

  char* ws = (char*)d_ws;
  const size_t MB = 1ull << 20;
  const size_t NW = 1ull << 20;
  unsigned short* wT   = (unsigned short*)(ws);             // 14MB
  unsigned short* xb   = (unsigned short*)(ws + 14 * MB);   // 16MB; later: ssm
  unsigned short* x1   = (unsigned short*)(ws + 30 * MB);   // 16MB; later: x_res
  unsigned short* xs   = (unsigned short*)(ws + 46 * MB);   // 16MB; later: hb
  float*          Abar = (float*)(ws + 62 * MB);            // 32MB; later: x_resT + z
  unsigned short* Bx   = (unsigned short*)(ws + 94 * MB);   // 16MB
  unsigned short* xD   = (unsigned short*)(ws + 110 * MB);  // 16MB
  float*          cA   = (float*)(ws + 126 * MB);
  float*          cB   = (float*)(ws + 126 * MB + 512 * 1024);
  float*          carry= (float*)(ws + 127 * MB);
  float*          cwT  = (float*)(ws + 127 * MB + 512 * 1024);  // 12KB
  unsigned short* hb    = xs;
  unsigned short* ssm   = xb;
  unsigned short* xres  = x1;
  unsigned short* xresT = (unsigned short*)(ws + 62 * MB);
  unsigned short* z     = (unsigned short*)(ws + 78 * MB);

  dim3 bT(32, 8);
  dim3 gG(8, 64);    // nwg=512, 2 blocks/CU

  k_prep_w<<<dim3(32, 32, 7), bT, 0, stream>>>(w1, wdelta, wB, wD, wC, w2, w_last, wT);
  k_prep_cw<<<12, 256, 0, stream>>>(conv_w, cwT);
  k_cast_x<<<8192, 256, 0, stream>>>(x, xb);
  // x1 = xb @ w1
  k_gemm<0, false><<<gG, 256, 0, stream>>>(xb, wT + 0 * NW, x1, nullptr, nullptr);
  // xs = silu(conv(x1))
  k_conv_silu<<<4096, 256, 0, stream>>>(x1, cwT, conv_b, xs);
  // A_bar = exp(-softplus(xs@wdelta + bdelta) * A)   (f32)
  k_gemm<1, false><<<gG, 256, 0, stream>>>(xs, wT + 1 * NW, Abar, bdelta, (const void*)Avec);
  // Bx = xs@wB + bB   (bf16)
  k_gemm<2, false><<<gG, 256, 0, stream>>>(xs, wT + 2 * NW, Bx, bB, nullptr);
  // xD = xs@wD + bD   (bf16)
  k_gemm<2, false><<<gG, 256, 0, stream>>>(xs, wT + 3 * NW, xD, bD, nullptr);
  // scan -> hb
  k_scan1<<<512, 256, 0, stream>>>(Abar, Bx, cA, cB);
  k_scan2<<<32, 256, 0, stream>>>(cA, cB, carry);
  k_scan3<<<512, 256, 0, stream>>>(Abar, Bx, carry, hb);
  // ssm = hb@wC + bC + xD
  k_gemm<3, false><<<gG, 256, 0, stream>>>(hb, wT + 4 * NW, ssm, bC, (const void*)xD);
  // x_res = silu(ssm@w2)
  k_gemm<4, false><<<gG, 256, 0, stream>>>(ssm, wT + 5 * NW, xres, nullptr, nullptr);
  // x_resT per batch
  k_transpose_xres<<<dim3(32, 32, 8), bT, 0, stream>>>(xres, xresT);
  // z = ssm @ x_res (batched via B^T = x_resT)
  k_gemm<0, true><<<gG, 256, 0, stream>>>(ssm, xresT, z, nullptr, nullptr);
  // out = z @ w_last (f32)
  k_gemm<5, false><<<gG, 256, 0, stream>>>(z, wT + 6 * NW, (float*)d_out, nullptr, nullptr);
}

// Round 5
// 254.374 us; speedup vs baseline: 1.3483x; 1.0738x over previous
//
#include <hip/hip_runtime.h>

// ---------- types / helpers ----------
typedef __bf16 bf16x8 __attribute__((ext_vector_type(8)));
typedef float  f32x4  __attribute__((ext_vector_type(4)));
typedef unsigned short u16x8 __attribute__((ext_vector_type(8)));

__device__ __forceinline__ float b2f(unsigned short u) {
  union { float f; unsigned int i; } v; v.i = ((unsigned int)u) << 16; return v.f;
}
__device__ __forceinline__ unsigned short f2b(float f) {
  union { float f; unsigned int i; } v; v.f = f;
  unsigned int r = v.i + 0x7fffu + ((v.i >> 16) & 1u);   // RNE
  return (unsigned short)(r >> 16);
}

__device__ __forceinline__ void async_copy16(const unsigned short* g, unsigned short* l) {
  __builtin_amdgcn_global_load_lds(
      (__attribute__((address_space(1))) void*)g,
      (__attribute__((address_space(3))) void*)l, 16, 0, 0);
}

// ---------- weight prep: transpose+cast 7 f32 [K][N] -> bf16 [N][K] ----------
__global__ void k_prep_w(const float* w0, const float* w1_, const float* w2_,
                         const float* w3_, const float* w4_, const float* w5_,
                         const float* w6_, unsigned short* dst) {
  const float* srcs[7] = {w0, w1_, w2_, w3_, w4_, w5_, w6_};
  const float* src = srcs[blockIdx.z];
  unsigned short* d = dst + ((size_t)blockIdx.z << 20);
  __shared__ float tile[32][33];
  const int bn = blockIdx.x << 5, bk = blockIdx.y << 5;
  const int tx = threadIdx.x, ty = threadIdx.y;   // 32 x 8
#pragma unroll
  for (int i = 0; i < 4; ++i)
    tile[ty + i * 8][tx] = src[(size_t)(bk + ty + i * 8) * 1024 + bn + tx];
  __syncthreads();
#pragma unroll
  for (int i = 0; i < 4; ++i)
    d[(size_t)(bn + ty + i * 8) * 1024 + bk + tx] = f2b(tile[tx][ty + i * 8]);
}

// ---------- conv weight transpose: cwT[j*1024+d] = conv_w[d*3+j] ----------
__global__ void k_prep_cw(const float* __restrict__ cw, float* __restrict__ cwT) {
  const int idx = blockIdx.x * 256 + threadIdx.x;   // 3072
  const int d = idx & 1023, j = idx >> 10;
  cwT[idx] = cw[d * 3 + j];
}

// ---------- cast x [8,1022,1024] f32 -> xb [8,1024,1024] bf16 (rows 1022/1023 zero) ----------
__global__ void k_cast_x(const float* __restrict__ x, unsigned short* __restrict__ xb) {
  const size_t i = ((size_t)blockIdx.x * 256 + threadIdx.x) << 2;
  const int d = (int)(i & 1023);
  const int row = (int)(i >> 10);
  const int t = row & 1023, b = row >> 10;
  float4 v = make_float4(0.f, 0.f, 0.f, 0.f);
  if (t < 1022) v = *(const float4*)&x[((size_t)(b * 1022 + t) << 10) + d];
  ushort4 o;
  o.x = f2b(v.x); o.y = f2b(v.y); o.z = f2b(v.z); o.w = f2b(v.w);
  *(ushort4*)&xb[i] = o;
}

// ---------- depthwise conv (k=3) + silu, vectorized x8 ----------
__global__ void k_conv_silu(const unsigned short* __restrict__ x1, const float* __restrict__ cwT,
                            const float* __restrict__ cb, unsigned short* __restrict__ xs) {
  const int gid = blockIdx.x * 256 + threadIdx.x;   // 8192 rows * 128 thr
  const int row = gid >> 7;
  const int d0 = (gid & 127) << 3;
  const int b = row >> 10, i = row & 1023;
  float acc[8];
  {
    float4 c0 = *(const float4*)&cb[d0], c1 = *(const float4*)&cb[d0 + 4];
    acc[0] = c0.x; acc[1] = c0.y; acc[2] = c0.z; acc[3] = c0.w;
    acc[4] = c1.x; acc[5] = c1.y; acc[6] = c1.z; acc[7] = c1.w;
  }
#pragma unroll
  for (int j = 0; j < 3; ++j) {
    const int t = i + j - 2;
    if (t >= 0) {
      u16x8 v = *(const u16x8*)&x1[((size_t)(b * 1024 + t) << 10) + d0];
      float4 w0 = *(const float4*)&cwT[j * 1024 + d0];
      float4 w1 = *(const float4*)&cwT[j * 1024 + d0 + 4];
      acc[0] += b2f(v[0]) * w0.x; acc[1] += b2f(v[1]) * w0.y;
      acc[2] += b2f(v[2]) * w0.z; acc[3] += b2f(v[3]) * w0.w;
      acc[4] += b2f(v[4]) * w1.x; acc[5] += b2f(v[5]) * w1.y;
      acc[6] += b2f(v[6]) * w1.z; acc[7] += b2f(v[7]) * w1.w;
    }
  }
  u16x8 o;
#pragma unroll
  for (int k = 0; k < 8; ++k) {
    float s = acc[k] / (1.f + __expf(-acc[k]));
    o[k] = f2b(s);
  }
  *(u16x8*)&xs[((size_t)row << 10) + d0] = o;
}

// ---------- chunked scan ----------
__global__ void k_scan1(const float* __restrict__ Abar, const unsigned short* __restrict__ Bx,
                        float* __restrict__ cA, float* __restrict__ cB) {
  const int g = blockIdx.x * 256 + threadIdx.x;   // 8*16*1024
  const int d = g & 1023, bc = g >> 10;
  const int b = bc >> 4, c = bc & 15;
  size_t base = ((size_t)(b * 1024 + c * 64) << 10) + d;
  float aA = 1.f, aB = 0.f;
  for (int t = 0; t < 64; ++t) {
    float a = Abar[base], bx = b2f(Bx[base]);
    aA *= a; aB = a * aB + bx; base += 1024;
  }
  cA[g] = aA; cB[g] = aB;
}
__global__ void k_scan2(const float* __restrict__ cA, const float* __restrict__ cB,
                        float* __restrict__ carry) {
  const int g = blockIdx.x * 256 + threadIdx.x;   // 8192
  const int d = g & 1023, b = g >> 10;
  float a[16], bb[16];
#pragma unroll
  for (int c = 0; c < 16; ++c) {
    const int idx = ((b * 16 + c) << 10) + d;
    a[c] = cA[idx]; bb[c] = cB[idx];
  }
  float sB = 0.f;
#pragma unroll
  for (int c = 0; c < 16; ++c) {
    carry[((b * 16 + c) << 10) + d] = sB;
    sB = a[c] * sB + bb[c];
  }
}
__global__ void k_scan3(const float* __restrict__ Abar, const unsigned short* __restrict__ Bx,
                        const float* __restrict__ carry, unsigned short* __restrict__ hb) {
  const int g = blockIdx.x * 256 + threadIdx.x;
  const int d = g & 1023, bc = g >> 10;
  const int b = bc >> 4, c = bc & 15;
  size_t base = ((size_t)(b * 1024 + c * 64) << 10) + d;
  float h = carry[g];
  for (int t = 0; t < 64; ++t) {
    float a = Abar[base], bx = b2f(Bx[base]);
    h = a * h + bx;
    hb[base] = f2b(h);
    base += 1024;
  }
}

// ---------- transpose x_res per batch ----------
__global__ void k_transpose_xres(const unsigned short* __restrict__ src,
                                 unsigned short* __restrict__ dst) {
  __shared__ unsigned short tile[32][33];
  const int b = blockIdx.z;
  const int bx = blockIdx.x << 5, by = blockIdx.y << 5;
  const int tx = threadIdx.x, ty = threadIdx.y;   // 32 x 8
  const unsigned short* s = src + ((size_t)b << 20);
  unsigned short* d = dst + ((size_t)b << 20);
#pragma unroll
  for (int i = 0; i < 4; ++i)
    tile[ty + i * 8][tx] = s[(size_t)(by + ty + i * 8) * 1024 + bx + tx];
  __syncthreads();
#pragma unroll
  for (int i = 0; i < 4; ++i)
    d[(size_t)(bx + ty + i * 8) * 1024 + by + tx] = tile[tx][ty + i * 8];
}

// ---------- GEMM: C[8192 x 1024] = A[8192x1024](bf16) * Bt[1024 x 1024]^T(bf16) ----------
// 128x128 tile, BK=64, 4 waves. 2-deep counted-vmcnt pipeline, raw barriers,
// XOR chunk swizzle (0 conflicts), persistent staging pointers.
// OPERAND-SWAPPED MFMA: acc=mfma(bF,aF,acc) -> lane holds row=l&15, 4 consecutive
// cols (kg*4+r) => vectorized float4/ushort4 epilogue stores (64B segs per 4 lanes).
// EPI: 0 bf16; 1 A_bar=exp(-softplus(v+aux1)*aux2) f32; 2 bf16(v+aux1);
//      3 bf16(v+aux1+bf16 aux2[idx]); 4 bf16(silu(v)); 5 f32.
template <int EPI, bool BATCHB>
__global__ __launch_bounds__(256)
void k_gemm(const unsigned short* __restrict__ A, const unsigned short* __restrict__ Bt,
            void* __restrict__ outp, const float* __restrict__ aux1,
            const void* __restrict__ aux2) {
  __shared__ unsigned short As[2][128 * 64];
  __shared__ unsigned short Bs[2][128 * 64];
  const int tid = threadIdx.x;

  // XCD chunking + m-fastest order inside 8-m-block groups (A-slice 2MB + B 2MB = L2-fit)
  const int nxb = gridDim.x;
  const int nwg = nxb * gridDim.y;
  int lin = blockIdx.y * nxb + blockIdx.x;
  lin = (lin & 7) * (nwg >> 3) + (lin >> 3);
  const int CH = nxb << 3;
  const int grp = lin / CH, idx = lin % CH;
  const int m0 = ((grp << 3) + (idx & 7)) << 7;
  const int n0 = (idx >> 3) << 7;

  const int wid = tid >> 6, l = tid & 63;
  const int wr = ((wid >> 1) << 6);
  const int wc = ((wid & 1) << 6);
  const int lr = l & 15, kg = l >> 4;
  const unsigned short* Bp = BATCHB ? Bt + ((size_t)(m0 >> 10) << 20) : Bt;

  f32x4 acc[4][4];
#pragma unroll
  for (int i = 0; i < 4; ++i)
#pragma unroll
    for (int j = 0; j < 4; ++j) acc[i][j] = (f32x4){0.f, 0.f, 0.f, 0.f};

  // staging: 16B/thread/it-block; LDS dest linear; global source chunk XOR-pre-swizzled.
  const int frow = tid >> 3;
  const int fchunk = (tid & 7) ^ (frow & 7);
  const unsigned short* ga[4];
  const unsigned short* gb[4];
#pragma unroll
  for (int it = 0; it < 4; ++it) {
    ga[it] = A  + (size_t)(m0 + frow + it * 32) * 1024 + (fchunk << 3);
    gb[it] = Bp + (size_t)(n0 + frow + it * 32) * 1024 + (fchunk << 3);
  }

#define STAGE(buf)                                                              \
  {                                                                             \
    _Pragma("unroll")                                                           \
    for (int it = 0; it < 4; ++it)                                              \
      async_copy16(ga[it], &As[buf][(tid << 3) + it * 2048]);                   \
    _Pragma("unroll")                                                           \
    for (int it = 0; it < 4; ++it)                                              \
      async_copy16(gb[it], &Bs[buf][(tid << 3) + it * 2048]);                   \
    _Pragma("unroll")                                                           \
    for (int it = 0; it < 4; ++it) { ga[it] += 64; gb[it] += 64; }              \
  }

  // loop-invariant LDS read byte-offsets
  const int c0 = kg ^ (lr & 7);
  const int aOff0 = ((wr + lr) << 7) + (c0 << 4);
  const int aOff1 = aOff0 ^ 64;
  const int bOff0 = ((wc + lr) << 7) + (c0 << 4);
  const int bOff1 = bOff0 ^ 64;
  const char* AsB = (const char*)&As[0][0];
  const char* BsB = (const char*)&Bs[0][0];

  STAGE(0);
  STAGE(1);   // 16 loads/thread in flight

#pragma unroll
  for (int t = 0; t < 16; ++t) {
    const int cur = t & 1;
    if (t < 15) asm volatile("s_waitcnt vmcnt(8)" ::: "memory");
    else        asm volatile("s_waitcnt vmcnt(0)" ::: "memory");
    __builtin_amdgcn_s_barrier();
    __builtin_amdgcn_sched_barrier(0);
    __builtin_amdgcn_s_setprio(1);
    const char* pa = AsB + (cur << 14);
    const char* pb = BsB + (cur << 14);
    {
      bf16x8 aF[4], bF[4];
#pragma unroll
      for (int mi = 0; mi < 4; ++mi) aF[mi] = *(const bf16x8*)(pa + aOff0 + mi * 2048);
#pragma unroll
      for (int ni = 0; ni < 4; ++ni) bF[ni] = *(const bf16x8*)(pb + bOff0 + ni * 2048);
#pragma unroll
      for (int mi = 0; mi < 4; ++mi)
#pragma unroll
        for (int ni = 0; ni < 4; ++ni)
          acc[mi][ni] = __builtin_amdgcn_mfma_f32_16x16x32_bf16(bF[ni], aF[mi], acc[mi][ni], 0, 0, 0);
    }
    {
      bf16x8 aF[4], bF[4];
#pragma unroll
      for (int mi = 0; mi < 4; ++mi) aF[mi] = *(const bf16x8*)(pa + aOff1 + mi * 2048);
#pragma unroll
      for (int ni = 0; ni < 4; ++ni) bF[ni] = *(const bf16x8*)(pb + bOff1 + ni * 2048);
#pragma unroll
      for (int mi = 0; mi < 4; ++mi)
#pragma unroll
        for (int ni = 0; ni < 4; ++ni)
          acc[mi][ni] = __builtin_amdgcn_mfma_f32_16x16x32_bf16(bF[ni], aF[mi], acc[mi][ni], 0, 0, 0);
    }
    __builtin_amdgcn_s_setprio(0);
    asm volatile("s_waitcnt lgkmcnt(0)" ::: "memory");
    __builtin_amdgcn_s_barrier();
    __builtin_amdgcn_sched_barrier(0);
    if (t + 2 < 16) STAGE(cur);
  }
#undef STAGE

  // epilogue (operand-swapped layout): lane l, frag (mi,ni), reg r holds
  // C[m0+wr+mi*16+(l&15)][n0+wc+ni*16+(l>>4)*4+r] -> 4 consecutive cols.
#pragma unroll
  for (int mi = 0; mi < 4; ++mi) {
    const int row = m0 + wr + mi * 16 + lr;
    const size_t rbase = (size_t)row << 10;
#pragma unroll
    for (int ni = 0; ni < 4; ++ni) {
      const int colb = n0 + wc + ni * 16 + (kg << 2);
      const f32x4 v = acc[mi][ni];
      if (EPI == 0) {
        ushort4 o; o.x = f2b(v[0]); o.y = f2b(v[1]); o.z = f2b(v[2]); o.w = f2b(v[3]);
        *(ushort4*)&((unsigned short*)outp)[rbase + colb] = o;
      } else if (EPI == 1) {
        const float4 b4 = *(const float4*)&aux1[colb];
        const float4 a4 = *(const float4*)&((const float*)aux2)[colb];
        float4 o;
        {
          float t0 = v[0] + b4.x; float sp = (t0 > 15.f) ? t0 : __logf(1.f + __expf(t0));
          o.x = __expf(-sp * a4.x);
          float t1 = v[1] + b4.y; sp = (t1 > 15.f) ? t1 : __logf(1.f + __expf(t1));
          o.y = __expf(-sp * a4.y);
          float t2 = v[2] + b4.z; sp = (t2 > 15.f) ? t2 : __logf(1.f + __expf(t2));
          o.z = __expf(-sp * a4.z);
          float t3 = v[3] + b4.w; sp = (t3 > 15.f) ? t3 : __logf(1.f + __expf(t3));
          o.w = __expf(-sp * a4.w);
        }
        *(float4*)&((float*)outp)[rbase + colb] = o;
      } else if (EPI == 2) {
        const float4 b4 = *(const float4*)&aux1[colb];
        ushort4 o;
        o.x = f2b(v[0] + b4.x); o.y = f2b(v[1] + b4.y);
        o.z = f2b(v[2] + b4.z); o.w = f2b(v[3] + b4.w);
        *(ushort4*)&((unsigned short*)outp)[rbase + colb] = o;
      } else if (EPI == 3) {
        const float4 b4 = *(const float4*)&aux1[colb];
        const ushort4 xv = *(const ushort4*)&((const unsigned short*)aux2)[rbase + colb];
        ushort4 o;
        o.x = f2b(v[0] + b4.x + b2f(xv.x)); o.y = f2b(v[1] + b4.y + b2f(xv.y));
        o.z = f2b(v[2] + b4.z + b2f(xv.z)); o.w = f2b(v[3] + b4.w + b2f(xv.w));
        *(ushort4*)&((unsigned short*)outp)[rbase + colb] = o;
      } else if (EPI == 4) {
        ushort4 o;
        o.x = f2b(v[0] / (1.f + __expf(-v[0]))); o.y = f2b(v[1] / (1.f + __expf(-v[1])));
        o.z = f2b(v[2] / (1.f + __expf(-v[2]))); o.w = f2b(v[3] / (1.f + __expf(-v[3])));
        *(ushort4*)&((unsigned short*)outp)[rbase + colb] = o;
      } else {
        float4 o; o.x = v[0]; o.y = v[1]; o.z = v[2]; o.w = v[3];
        *(float4*)&((float*)outp)[rbase + colb] = o;
      }
    }
  }
}

// ---------- launch ----------
extern "C" void kernel_launch(void* const* d_in, const int* in_sizes, int n_in,
                              void* d_out, int out_size, void* d_ws, size_t ws_size,
                              hipStream_t stream) {
  const float* x      = (const float*)d_in[0];
  const float* w1     = (const float*)d_in[1];
  const float* w2     = (const float*)d_in[2];
  const float* w_last = (const float*)d_in[3];
  const float* conv_w = (const float*)d_in[4];
  const float* conv_b = (const float*)d_in[5];
  const float* Avec   = (const float*)d_in[6];
  const float* wB     = (const float*)d_in[7];
  const float* bB     = (const float*)d_in[8];
  const float* wC     = (const float*)d_in[9];
  const float* bC     = (const float*)d_in[10];
  const float* wD     = (const float*)d_in[11];
  const float* bD     = (const float*)d_in[12];
  const float* wdelta = (const float*)d_in[13];
  const float* bdelta = (const float*)d_in[14];

  char* ws = (char*)d_ws;
  const size_t MB = 1ull << 20;
  const size_t NW = 1ull << 20;
  unsigned short* wT   = (unsigned short*)(ws);             // 14MB
  unsigned short* xb   = (unsigned short*)(ws + 14 * MB);   // 16MB; later: ssm
  unsigned short* x1   = (unsigned short*)(ws + 30 * MB);   // 16MB; later: x_res
  unsigned short* xs   = (unsigned short*)(ws + 46 * MB);   // 16MB; later: hb
  float*          Abar = (float*)(ws + 62 * MB);            // 32MB; later: x_resT + z
  unsigned short* Bx   = (unsigned short*)(ws + 94 * MB);   // 16MB
  unsigned short* xD   = (unsigned short*)(ws + 110 * MB);  // 16MB
  float*          cA   = (float*)(ws + 126 * MB);
  float*          cB   = (float*)(ws + 126 * MB + 512 * 1024);
  float*          carry= (float*)(ws + 127 * MB);
  float*          cwT  = (float*)(ws + 127 * MB + 512 * 1024);  // 12KB
  unsigned short* hb    = xs;
  unsigned short* ssm   = xb;
  unsigned short* xres  = x1;
  unsigned short* xresT = (unsigned short*)(ws + 62 * MB);
  unsigned short* z     = (unsigned short*)(ws + 78 * MB);

  dim3 bT(32, 8);
  dim3 gG(8, 64);    // nwg=512, 2 blocks/CU

  k_prep_w<<<dim3(32, 32, 7), bT, 0, stream>>>(w1, wdelta, wB, wD, wC, w2, w_last, wT);
  k_prep_cw<<<12, 256, 0, stream>>>(conv_w, cwT);
  k_cast_x<<<8192, 256, 0, stream>>>(x, xb);
  // x1 = xb @ w1
  k_gemm<0, false><<<gG, 256, 0, stream>>>(xb, wT + 0 * NW, x1, nullptr, nullptr);
  // xs = silu(conv(x1))
  k_conv_silu<<<4096, 256, 0, stream>>>(x1, cwT, conv_b, xs);
  // A_bar = exp(-softplus(xs@wdelta + bdelta) * A)   (f32)
  k_gemm<1, false><<<gG, 256, 0, stream>>>(xs, wT + 1 * NW, Abar, bdelta, (const void*)Avec);
  // Bx = xs@wB + bB   (bf16)
  k_gemm<2, false><<<gG, 256, 0, stream>>>(xs, wT + 2 * NW, Bx, bB, nullptr);
  // xD = xs@wD + bD   (bf16)
  k_gemm<2, false><<<gG, 256, 0, stream>>>(xs, wT + 3 * NW, xD, bD, nullptr);
  // scan -> hb
  k_scan1<<<512, 256, 0, stream>>>(Abar, Bx, cA, cB);
  k_scan2<<<32, 256, 0, stream>>>(cA, cB, carry);
  k_scan3<<<512, 256, 0, stream>>>(Abar, Bx, carry, hb);
  // ssm = hb@wC + bC + xD
  k_gemm<3, false><<<gG, 256, 0, stream>>>(hb, wT + 4 * NW, ssm, bC, (const void*)xD);
  // x_res = silu(ssm@w2)
  k_gemm<4, false><<<gG, 256, 0, stream>>>(ssm, wT + 5 * NW, xres, nullptr, nullptr);
  // x_resT per batch
  k_transpose_xres<<<dim3(32, 32, 8), bT, 0, stream>>>(xres, xresT);
  // z = ssm @ x_res (batched via B^T = x_resT)
  k_gemm<0, true><<<gG, 256, 0, stream>>>(ssm, xresT, z, nullptr, nullptr);
  // out = z @ w_last (f32)
  k_gemm<5, false><<<gG, 256, 0, stream>>>(z, wT + 6 * NW, (float*)d_out, nullptr, nullptr);
}